// Round 1
// baseline (8002.490 us; speedup 1.0000x reference)
//
#include <hip/hip_runtime.h>
#include <hip/hip_bf16.h>

#define T_LEN 512
#define NB 64      // batch
#define FB 256     // input features
#define SB 1024    // hidden size
// combined K = FB + SB = 1280, processed in 40 chunks of 32

typedef __attribute__((ext_vector_type(8))) short bf16x8;
typedef __attribute__((ext_vector_type(4))) float f32x4;

// ---------------- prep: x -> MFMA A-fragment order, bf16 ----------------
// XAf[t][m(4)][kc(8)][lane*8+e] ; element = x[t][m*16+(l&15)][kc*32+8*(l>>4)+e]
__global__ void xfrag_kernel(const float* __restrict__ x, __hip_bfloat16* __restrict__ xaf) {
    int tid  = blockIdx.x * 256 + threadIdx.x;   // total T*4*8*64 = 1,048,576
    int l    = tid & 63;
    int frag = tid >> 6;                         // t*32 + m*8 + kc
    int kc   = frag & 7;
    int m    = (frag >> 3) & 3;
    int t    = frag >> 5;
    int row  = m * 16 + (l & 15);
    int k0   = kc * 32 + 8 * (l >> 4);
    const float* src = x + ((size_t)(t * NB + row)) * FB + k0;
    __hip_bfloat16* dst = xaf + (size_t)frag * 512 + l * 8;
#pragma unroll
    for (int e = 0; e < 8; ++e) dst[e] = __float2bfloat16(src[e]);
}

// ------------- prep: [Wx;Wh] -> MFMA B-fragment order, bf16 -------------
// WBf[g(4)][sb(64)][kc(40)][lane*8+e]; k = kc*32+8*(l>>4)+e ; s = sb*16+(l&15)
// k < 256 -> Wx[g][k][s], else Wh[g][k-256][s]
__global__ void wfrag_kernel(const float* __restrict__ Wx, const float* __restrict__ Wh,
                             __hip_bfloat16* __restrict__ wbf) {
    int tid  = blockIdx.x * 256 + threadIdx.x;   // total 4*64*40*64 = 655,360
    int l    = tid & 63;
    int frag = tid >> 6;                         // (g*64 + sb)*40 + kc
    int kc   = frag % 40;
    int sb   = (frag / 40) & 63;
    int g    = frag / (40 * 64);
    int s    = sb * 16 + (l & 15);
    int k0   = kc * 32 + 8 * (l >> 4);
    __hip_bfloat16* dst = wbf + (size_t)frag * 512 + l * 8;
#pragma unroll
    for (int e = 0; e < 8; ++e) {
        int k = k0 + e;
        float v = (k < FB) ? Wx[((size_t)g * FB + k) * SB + s]
                           : Wh[((size_t)g * SB + (k - FB)) * SB + s];
        dst[e] = __float2bfloat16(v);
    }
}

// ---------------- one LSTM time step ----------------
// grid 64 (s-blocks of 16 columns), block 256 (4 waves; wave w computes gate w)
__global__ __launch_bounds__(256) void lstm_step(
    const __hip_bfloat16* __restrict__ xaf_t,  // [4 m][8 kc][512] for this t
    const __hip_bfloat16* __restrict__ wbf,    // fragment-ordered weights
    const float* __restrict__ bias,            // [4][1024]
    const __hip_bfloat16* __restrict__ h_in,   // [64][1024]
    __hip_bfloat16* __restrict__ h_out,        // [64][1024]
    float* __restrict__ c_io,                  // [64][1024] fp32
    float* __restrict__ out_t)                 // [64][1024] fp32 (d_out + t*65536)
{
    __shared__ uint4 lds4[8192];               // 128 KiB
    char* lds = (char*)lds4;
    const int tid = threadIdx.x;
    const int w   = tid >> 6;                  // wave = gate index
    const int l   = tid & 63;
    const int sb  = blockIdx.x;                // s-block 0..63
    const int lr  = l & 15;                    // tile row / col within fragment
    const int lg  = l >> 4;                    // k subgroup 0..3
    const int xr  = lr & 7;                    // swizzle key (row&7 for all m-tiles)

    // ---- stage h into LDS: rows n=0..63, 128 16B-slots/row, slot j stored at j^(row&7)
#pragma unroll
    for (int i = 0; i < 32; ++i) {
        int sl  = i * 256 + tid;               // 16B-slot id 0..8191 (coalesced global)
        int row = sl >> 7;
        int jj  = sl & 127;
        uint4 v = *reinterpret_cast<const uint4*>(h_in + (size_t)sl * 8);
        *reinterpret_cast<uint4*>(lds + row * 2048 + ((jj ^ (row & 7)) << 4)) = v;
    }
    __syncthreads();

    // ---- GEMM: z[g] = [64 x 1280] @ [1280 x 16] via 16x16x32 bf16 MFMA
    f32x4 acc0 = {0.f,0.f,0.f,0.f}, acc1 = acc0, acc2 = acc0, acc3 = acc0;
    const __hip_bfloat16* wp = wbf + ((size_t)(w * 64 + sb) * 40) * 512 + l * 8;
#pragma unroll 4
    for (int kc = 0; kc < 40; ++kc) {
        bf16x8 bfr = *reinterpret_cast<const bf16x8*>(wp + (size_t)kc * 512);
        bf16x8 a0, a1, a2, a3;
        if (kc < 8) {
            // x part: fragment-ordered global loads (coalesced, 4x wave-redundant but small)
            const __hip_bfloat16* xp = xaf_t + (size_t)kc * 512 + l * 8;
            a0 = *reinterpret_cast<const bf16x8*>(xp);
            a1 = *reinterpret_cast<const bf16x8*>(xp + 4096);
            a2 = *reinterpret_cast<const bf16x8*>(xp + 8192);
            a3 = *reinterpret_cast<const bf16x8*>(xp + 12288);
        } else {
            // h part from swizzled LDS
            int j = (kc - 8) * 4 + lg;
            int jx = (j ^ xr) << 4;
            a0 = *reinterpret_cast<const bf16x8*>(lds + (lr)      * 2048 + jx);
            a1 = *reinterpret_cast<const bf16x8*>(lds + (16 + lr) * 2048 + jx);
            a2 = *reinterpret_cast<const bf16x8*>(lds + (32 + lr) * 2048 + jx);
            a3 = *reinterpret_cast<const bf16x8*>(lds + (48 + lr) * 2048 + jx);
        }
        acc0 = __builtin_amdgcn_mfma_f32_16x16x32_bf16(a0, bfr, acc0, 0, 0, 0);
        acc1 = __builtin_amdgcn_mfma_f32_16x16x32_bf16(a1, bfr, acc1, 0, 0, 0);
        acc2 = __builtin_amdgcn_mfma_f32_16x16x32_bf16(a2, bfr, acc2, 0, 0, 0);
        acc3 = __builtin_amdgcn_mfma_f32_16x16x32_bf16(a3, bfr, acc3, 0, 0, 0);
    }

    // ---- exchange z through LDS (reuse h buffer: all reads done)
    __syncthreads();
    float* zb = (float*)lds;                   // [4 gates][64 n][16 sc]
#pragma unroll
    for (int i = 0; i < 4; ++i) {
        int rbase = w * 64 + lg * 4 + i;
        zb[(rbase)      * 16 + lr] = acc0[i];  // m=0 rows 0..15
        zb[(rbase + 16) * 16 + lr] = acc1[i];
        zb[(rbase + 32) * 16 + lr] = acc2[i];
        zb[(rbase + 48) * 16 + lr] = acc3[i];
    }
    __syncthreads();

    // ---- gates + state update (fp32)
    const int s0 = sb * 16;
#pragma unroll
    for (int r = 0; r < 4; ++r) {
        int p  = r * 256 + tid;                // 0..1023
        int n  = p >> 4;
        int sc = p & 15;
        int sg = s0 + sc;
        float zi = zb[(n)       * 16 + sc] + bias[sg];
        float zf = zb[(64 + n)  * 16 + sc] + bias[SB + sg];
        float zg = zb[(128 + n) * 16 + sc] + bias[2 * SB + sg];
        float zo = zb[(192 + n) * 16 + sc] + bias[3 * SB + sg];
        float ig = 1.f / (1.f + expf(-zi));
        float fg = 1.f / (1.f + expf(-zf));
        float gg = tanhf(zg);
        float og = 1.f / (1.f + expf(-zo));
        int idx = n * SB + sg;
        float c = fg * c_io[idx] + ig * gg;
        float h = og * tanhf(c);
        c_io[idx]  = c;
        h_out[idx] = __float2bfloat16(h);
        out_t[idx] = h;
    }
}

extern "C" void kernel_launch(void* const* d_in, const int* in_sizes, int n_in,
                              void* d_out, int out_size, void* d_ws, size_t ws_size,
                              hipStream_t stream) {
    const float* x  = (const float*)d_in[0];   // [512][64][256]
    const float* Wx = (const float*)d_in[1];   // [4][256][1024]
    const float* Wh = (const float*)d_in[2];   // [4][1024][1024]
    const float* b  = (const float*)d_in[3];   // [4][1024]
    float* out = (float*)d_out;                // [512][64][1024]

    char* ws = (char*)d_ws;
    __hip_bfloat16* xaf  = (__hip_bfloat16*)ws;                 // 16,777,216 B
    __hip_bfloat16* wbf  = (__hip_bfloat16*)(ws + 16777216);    // 10,485,760 B
    __hip_bfloat16* hbuf = (__hip_bfloat16*)(ws + 27262976);    // 2 x 131,072 B
    float*          cbuf = (float*)(ws + 27525120);             // 262,144 B
    // total ws use: ~27.8 MB

    hipLaunchKernelGGL(xfrag_kernel, dim3(4096), dim3(256), 0, stream, x, xaf);
    hipLaunchKernelGGL(wfrag_kernel, dim3(2560), dim3(256), 0, stream, Wx, Wh, wbf);
    hipMemsetAsync(hbuf, 0, 131072, stream);   // h0 = 0 (bf16 zero == 0x0000)
    hipMemsetAsync(cbuf, 0, 262144, stream);   // c0 = 0

    for (int t = 0; t < T_LEN; ++t) {
        const __hip_bfloat16* h_in = hbuf + (size_t)(t & 1) * (NB * SB);
        __hip_bfloat16* h_out      = hbuf + (size_t)((t + 1) & 1) * (NB * SB);
        hipLaunchKernelGGL(lstm_step, dim3(64), dim3(256), 0, stream,
                           xaf + (size_t)t * 16384, wbf, b,
                           h_in, h_out, cbuf,
                           out + (size_t)t * (NB * SB));
    }
}